// Round 6
// baseline (1035.582 us; speedup 1.0000x reference)
//
#include <hip/hip_runtime.h>

// LSTMAutoRegressive: B=1024, T=1024, H1=64, H2=32, n_in=n_out=1.
// v6: 64 wgs x 512 threads. MERGED-role waves (each: 2 L1 tiles + 1 L2 tile,
// wave0 += y) ordered so matrix and trans/VALU pipes overlap within a wave:
// [MFMA_L2(t-1)] [MFMA_L1(t)] [ACT_L2 while L1 drains] [ACT_L1]. Joint-rcp
// activations (7 trans/unit, was 10), c pre-scaled by 2log2e. exp2-folded
// weights, xd folded as a 7th MFMA k-step. One lgkm-only barrier per step.

using short8 = __attribute__((ext_vector_type(8))) short;
using f32x4  = __attribute__((ext_vector_type(4))) float;
typedef unsigned short us;
typedef unsigned int   uu;

#define MFMA16(A,B,C) __builtin_amdgcn_mfma_f32_16x16x32_bf16((A),(B),(C),0,0,0)
#define BARRIER() asm volatile("s_waitcnt lgkmcnt(0)\n\ts_barrier" ::: "memory")

constexpr int   T     = 1024;
constexpr float LOG2E = 1.44269504088896f;

__device__ __forceinline__ us    bhi(float f){ return (us)(__float_as_uint(f) >> 16); }
__device__ __forceinline__ float hmask(float f){ return __uint_as_float(__float_as_uint(f) & 0xFFFF0000u); }
// h1 LDS pos p -> unit: lane (w,lq,m) writes unit 8w+4m+lq at pos 8w+2lq+m
__device__ __forceinline__ int upos(int p){ return 8*(p>>3) + 4*(p&1) + ((p&7)>>1); }

__device__ __forceinline__ float rcpf(float x){ return __builtin_amdgcn_rcpf(x); }
#if __has_builtin(__builtin_amdgcn_exp2f)
__device__ __forceinline__ float ex2(float x){ return __builtin_amdgcn_exp2f(x); }
#else
__device__ __forceinline__ float ex2(float x){
    float r; asm("v_exp_f32 %0, %1\n\ts_nop 0" : "=v"(r) : "v"(x)); return r;
}
#endif

// gates pre-scaled: i,f,o by -log2e ; g by +2log2e. cs = 2log2e*c carried.
// Joint reciprocal: 1 rcp for all 4 gates (5 exp + 2 rcp total).
__device__ __forceinline__ float actf(const f32x4 a, float& cs){
    float Ei = ex2(a[0]), Ef = ex2(a[1]), Eg = ex2(a[2]), Eo = ex2(a[3]);
    float pi = 1.0f + Ei, pf = 1.0f + Ef, pg = 1.0f + Eg, po = 1.0f + Eo;
    float pif = pi * pf, pgo = pg * po;
    float r   = rcpf(pif * pgo);
    float rif = r * pgo, rgo = r * pif;
    float si = rif * pf, sf = rif * pi;
    float rg = rgo * po, so = rgo * pg;
    float gt2 = __builtin_fmaf(-4.0f * LOG2E, rg, 2.0f * LOG2E);   // 2log2e*tanh(g)
    cs = __builtin_fmaf(sf, cs, si * gt2);
    float Ec = ex2(cs);
    float tc = __builtin_fmaf(-2.0f, rcpf(1.0f + Ec), 1.0f);       // tanh(c)
    return so * tc;
}

__global__ __launch_bounds__(512, 2)
void lstm_ar_kernel(const float* __restrict__ x_in,
                    const float* __restrict__ dly_in,
                    const float* __restrict__ W_ih1, const float* __restrict__ W_hh1,
                    const float* __restrict__ b_ih1, const float* __restrict__ b_hh1,
                    const float* __restrict__ W_ih2, const float* __restrict__ W_hh2,
                    const float* __restrict__ b_ih2, const float* __restrict__ b_hh2,
                    const float* __restrict__ W_out, const float* __restrict__ b_out,
                    float* __restrict__ out)
{
    // h1 rows: pos-order (upos) [hi 0..63 | lo 64..127], stride 136 us.
    // h2 rows: plain unit order [hi 0..31 | lo 32..63],  stride 72 us.
    __shared__ __align__(16) us H1[2][16][136];
    __shared__ __align__(16) us H2[2][16][72];

    const int tid = threadIdx.x, w = tid >> 6, l = tid & 63;
    const int lb = l & 15, lq = l >> 4;
    const int bglob = blockIdx.x * 16 + lb;

    for (int i = tid; i < 2*16*136; i += 512) ((us*)H1)[i] = 0;
    for (int i = tid; i < 2*16*72;  i += 512) ((us*)H2)[i] = 0;

    const int ty = lb & 3, du = lb >> 2;
    const float srow = (ty == 2) ? 2.0f * LOG2E : -LOG2E;

    // ---- L1 frags: tiles m=0,1; gate-row G = ty*64 + 8w + 4m + du ----
    short8 w1h[2][2], w1l[2][2], wxd[2];
    #pragma unroll
    for (int m = 0; m < 2; ++m) {
        const int G = ty * 64 + 8 * w + 4 * m + du;
        #pragma unroll
        for (int s = 0; s < 2; ++s)
            #pragma unroll
            for (int i = 0; i < 8; ++i) {
                int p = 32*s + 8*lq + i;
                float v = srow * W_hh1[G * 64 + upos(p)];
                float vh = hmask(v);
                w1h[m][s][i] = (short)bhi(v);
                w1l[m][s][i] = (short)bhi(v - vh);
            }
        float q4 = 0.25f * srow;
        float wx = q4 * W_ih1[G*2+0], wd = q4 * W_ih1[G*2+1];
        float bb = q4 * (b_ih1[G] + b_hh1[G]);
        float wxh = hmask(wx), wdh = hmask(wd), bbh = hmask(bb);
        wxd[m] = (short8){ (short)bhi(wx), (short)bhi(wx), (short)bhi(wd),
                           (short)bhi(wd), (short)bhi(bb), (short)bhi(wx - wxh),
                           (short)bhi(wd - wdh), (short)bhi(bb - bbh) };
    }

    // ---- L2 frags: tile = wave; G2 = ty*32 + 4w + du ----
    short8 w2h[2], w2l[2], whh, whl, wb;
    {
        const int G2 = ty * 32 + 4 * w + du;
        #pragma unroll
        for (int s = 0; s < 2; ++s)
            #pragma unroll
            for (int i = 0; i < 8; ++i) {
                int p = 32*s + 8*lq + i;
                float v = srow * W_ih2[G2 * 64 + upos(p)];   // h1 pos-order
                float vh = hmask(v);
                w2h[s][i] = (short)bhi(v);
                w2l[s][i] = (short)bhi(v - vh);
            }
        #pragma unroll
        for (int i = 0; i < 8; ++i) {
            float v = srow * W_hh2[G2 * 32 + 8*lq + i];      // h2 plain order
            float vh = hmask(v);
            whh[i] = (short)bhi(v);
            whl[i] = (short)bhi(v - vh);
        }
        float bb = 0.25f * srow * (b_ih2[G2] + b_hh2[G2]);
        float bbh = hmask(bb);
        wb = (short8){ (short)bhi(bb), (short)bhi(bb - bbh), 0,0,0,0,0,0 };
    }

    // ---- y frags (wave 0): A row 0 = W_out, plain h2 order ----
    short8 wyh = {}, wyl = {};
    if (w == 0) {
        #pragma unroll
        for (int i = 0; i < 8; ++i) {
            float v = (lb == 0) ? W_out[8*lq + i] : 0.0f;
            float vh = hmask(v);
            wyh[i] = (short)bhi(v);
            wyl[i] = (short)bhi(v - vh);
        }
    }
    const float bout = b_out[0];
    const short8 bB = (short8){(short)0x3F80,(short)0x3F80,0,0,0,0,0,0};

    const float* xp = x_in   + bglob * T;
    const float* dp = dly_in + bglob * T;
    float*       op = out    + bglob * T;

    float c1a = 0.f, c1b = 0.f, c2s = 0.f;   // cs pre-scaled by 2log2e
    float2 xc = *(const float2*)xp, dc = *(const float2*)dp;

    __syncthreads();

    auto STEP = [&](const int t, const int pw, const int pr,
                    const float xv, const float dv) {
        const bool gL1 = (t < T), gL2 = (t >= 1 && t <= T);
        const us* r1 = &H1[pr][lb][0];   // h1(t-1)
        const us* r2 = &H2[pw][lb][0];   // h2(t-2)

        short8 hh0 = {}, hh1 = {}, hl0 = {}, hl1 = {}, g0 = {}, g1 = {};
        if (t <= T) {
            hh0 = *(const short8*)(r1 + 8*lq);
            hh1 = *(const short8*)(r1 + 32 + 8*lq);
            hl0 = *(const short8*)(r1 + 64 + 8*lq);
            hl1 = *(const short8*)(r1 + 96 + 8*lq);
        }
        if (t >= 1) {
            g0 = *(const short8*)(r2 + 8*lq);
            g1 = *(const short8*)(r2 + 32 + 8*lq);
        }

        // xd B-frag: [xhi,xlo,dhi,dlo,1,xhi,dhi,1] (quarter-replicated)
        uu xu = __float_as_uint(xv), duu = __float_as_uint(dv);
        float xlo = xv - __uint_as_float(xu & 0xFFFF0000u);
        float dlo = dv - __uint_as_float(duu & 0xFFFF0000u);
        short8 bx;
        ((uu*)&bx)[0] = (xu >> 16)  | (__float_as_uint(xlo) & 0xFFFF0000u);
        ((uu*)&bx)[1] = (duu >> 16) | (__float_as_uint(dlo) & 0xFFFF0000u);
        ((uu*)&bx)[2] = 0x00003F80u | (xu & 0xFFFF0000u);
        ((uu*)&bx)[3] = (duu >> 16) | 0x3F800000u;

        // ---- MFMA_L2(t-1): 3 chains (issue FIRST so ACT_L2 wakes early) ----
        f32x4 qA = {0,0,0,0}, qB = {0,0,0,0}, qC = {0,0,0,0};
        if (gL2) {
            qA = MFMA16(w2h[0], hh0, qA);
            qB = MFMA16(w2h[1], hh1, qB);
            qC = MFMA16(whh,    g0,  qC);
            qA = MFMA16(w2h[0], hl0, qA);
            qB = MFMA16(w2h[1], hl1, qB);
            qC = MFMA16(whh,    g1,  qC);
            qA = MFMA16(w2l[0], hh0, qA);
            qB = MFMA16(w2l[1], hh1, qB);
            qC = MFMA16(whl,    g0,  qC);
            qA = MFMA16(wb,     bB,  qA);
        }

        // ---- MFMA_L1(t): 4 chains (matrix pipe drains under ACT_L2) ----
        f32x4 aA0 = {0,0,0,0}, aB0 = {0,0,0,0};
        f32x4 aA1 = {0,0,0,0}, aB1 = {0,0,0,0};
        if (gL1) {
            aA0 = MFMA16(w1h[0][0], hh0, aA0);
            aB0 = MFMA16(w1h[0][1], hh1, aB0);
            aA1 = MFMA16(w1h[1][0], hh0, aA1);
            aB1 = MFMA16(w1h[1][1], hh1, aB1);
            aA0 = MFMA16(w1h[0][0], hl0, aA0);
            aB0 = MFMA16(w1h[0][1], hl1, aB0);
            aA1 = MFMA16(w1h[1][0], hl0, aA1);
            aB1 = MFMA16(w1h[1][1], hl1, aB1);
            aA0 = MFMA16(w1l[0][0], hh0, aA0);
            aB0 = MFMA16(w1l[0][1], hh1, aB0);
            aA1 = MFMA16(w1l[1][0], hh0, aA1);
            aB1 = MFMA16(w1l[1][1], hh1, aB1);
            aA0 = MFMA16(wxd[0], bx, aA0);
            aA1 = MFMA16(wxd[1], bx, aA1);
        }

        // ---- y MFMAs (wave 0) ----
        f32x4 yA = {0,0,0,0}, yB = {0,0,0,0};
        const bool gy = (w == 0 && t >= 2);
        if (gy) {
            yA = MFMA16(wyh, g0, yA);
            yB = MFMA16(wyh, g1, yB);
            yA = MFMA16(wyl, g0, yA);
        }

        // ---- ACT_L2(t-1) -> h2 write (overlaps matrix drain of L1) ----
        if (gL2) {
            f32x4 gg = { qA[0]+qB[0]+qC[0], qA[1]+qB[1]+qC[1],
                         qA[2]+qB[2]+qC[2], qA[3]+qB[3]+qC[3] };
            float h2v = actf(gg, c2s);
            uu u2 = __float_as_uint(h2v);
            H2[pr][lb][4*w + lq]      = (us)(u2 >> 16);
            float hf = __uint_as_float(u2 & 0xFFFF0000u);
            H2[pr][lb][32 + 4*w + lq] = bhi(h2v - hf);
        }

        // ---- y store ----
        if (gy && lq == 0) op[t-2] = yA[0] + yB[0] + bout;

        // ---- ACT_L1(t) -> packed h1 write (critical cycle closes) ----
        if (gL1) {
            f32x4 g0v = { aA0[0]+aB0[0], aA0[1]+aB0[1], aA0[2]+aB0[2], aA0[3]+aB0[3] };
            f32x4 g1v = { aA1[0]+aB1[0], aA1[1]+aB1[1], aA1[2]+aB1[2], aA1[3]+aB1[3] };
            float h0 = actf(g0v, c1a);
            float h1 = actf(g1v, c1b);
            uu ph = (__float_as_uint(h0) >> 16) | (__float_as_uint(h1) & 0xFFFF0000u);
            float e0 = h0 - hmask(h0), e1 = h1 - hmask(h1);
            uu pl = (__float_as_uint(e0) >> 16) | (__float_as_uint(e1) & 0xFFFF0000u);
            *(uu*)&H1[pw][lb][8*w + 2*lq]      = ph;
            *(uu*)&H1[pw][lb][64 + 8*w + 2*lq] = pl;
        }

        BARRIER();
    };

    #pragma unroll 1
    for (int tt = 0; tt <= 512; ++tt) {
        const int wn = (tt < 511) ? tt + 1 : 511;
        float2 xn = *(const float2*)(xp + 2*wn);
        float2 dn = *(const float2*)(dp + 2*wn);
        STEP(2*tt,     0, 1, xc.x, dc.x);
        STEP(2*tt + 1, 1, 0, xc.y, dc.y);
        xc = xn; dc = dn;
    }
}

extern "C" void kernel_launch(void* const* d_in, const int* in_sizes, int n_in,
                              void* d_out, int out_size, void* d_ws, size_t ws_size,
                              hipStream_t stream) {
    lstm_ar_kernel<<<dim3(64), dim3(512), 0, stream>>>(
        (const float*)d_in[0],  (const float*)d_in[1],
        (const float*)d_in[2],  (const float*)d_in[3],
        (const float*)d_in[4],  (const float*)d_in[5],
        (const float*)d_in[6],  (const float*)d_in[7],
        (const float*)d_in[8],  (const float*)d_in[9],
        (const float*)d_in[10], (const float*)d_in[11],
        (float*)d_out);
}

// Round 8
// 956.985 us; speedup vs baseline: 1.0821x; 1.0821x over previous
//
#include <hip/hip_runtime.h>

// LSTMAutoRegressive: B=1024, T=1024, H1=64, H2=32, n_in=n_out=1.
// v7b: compile fix of v7 (braced init inside macro arg -> ZERO4 constant).
// 64 wgs x 512 threads. ANTI-PHASE role split:
//   A-waves (0-3): layer-1, 4 tiles each.  B-waves (4-7): layer-2, 2 tiles + y.
// Interval t: [A: MFMA_L1(t) || B: ACT_L2 -> h2(t-2)]  BAR1
//             [A: ACT_L1 -> h1(t) || B: MFMA_L2 gates(t-1) + y(t-2)]  BAR2
// B's accumulators are register-carried across the interval boundary, so on
// every SIMD (1 A-wave + 1 B-wave) one wave drives the matrix pipe while the
// other drives VALU/trans in BOTH halves. sched_barrier(0) pins the halves.
// MFMA 16x16x32 bf16 swapped operands, gate-permuted A-rows, bf16 hi/lo,
// exp2-folded weights, joint-rcp activations, xd folded as 7th MFMA k-step.

using short8 = __attribute__((ext_vector_type(8))) short;
using f32x4  = __attribute__((ext_vector_type(4))) float;
typedef unsigned short us;
typedef unsigned int   uu;

#define MFMA16(A,B,C) __builtin_amdgcn_mfma_f32_16x16x32_bf16((A),(B),(C),0,0,0)
#define BARRIER() asm volatile("s_waitcnt lgkmcnt(0)\n\ts_barrier" ::: "memory")
#define SCHEDB()  __builtin_amdgcn_sched_barrier(0)

constexpr int   T     = 1024;
constexpr float LOG2E = 1.44269504088896f;

__device__ __forceinline__ us    bhi(float f){ return (us)(__float_as_uint(f) >> 16); }
__device__ __forceinline__ float hmask(float f){ return __uint_as_float(__float_as_uint(f) & 0xFFFF0000u); }
// h1 pos p <-> unit (A-layout: lane(w,lq) tiles m=0..3 -> pos 16w+4lq+m, unit 16w+4m+lq)
__device__ __forceinline__ int upos1(int p){ return 16*(p>>4) + 4*(p&3) + ((p>>2)&3); }
// h2 pos p <-> unit (B-layout: lane(w2,lq) tiles j=0..1 -> pos 8w2+2lq+j, unit 8w2+4j+lq)
__device__ __forceinline__ int upos2(int p){ return 8*(p>>3) + 4*(p&1) + ((p&7)>>1); }

__device__ __forceinline__ float rcpf(float x){ return __builtin_amdgcn_rcpf(x); }
#if __has_builtin(__builtin_amdgcn_exp2f)
__device__ __forceinline__ float ex2(float x){ return __builtin_amdgcn_exp2f(x); }
#else
__device__ __forceinline__ float ex2(float x){
    float r; asm("v_exp_f32 %0, %1\n\ts_nop 0" : "=v"(r) : "v"(x)); return r;
}
#endif

// gates pre-scaled: i,f,o by -log2e ; g by +2log2e. cs = 2log2e*c carried.
__device__ __forceinline__ float actf(const f32x4 a, float& cs){
    float Ei = ex2(a[0]), Ef = ex2(a[1]), Eg = ex2(a[2]), Eo = ex2(a[3]);
    float pi = 1.0f + Ei, pf = 1.0f + Ef, pg = 1.0f + Eg, po = 1.0f + Eo;
    float pif = pi * pf, pgo = pg * po;
    float r   = rcpf(pif * pgo);
    float rif = r * pgo, rgo = r * pif;
    float si = rif * pf, sf = rif * pi;
    float rg = rgo * po, so = rgo * pg;
    float gt2 = __builtin_fmaf(-4.0f * LOG2E, rg, 2.0f * LOG2E);
    cs = __builtin_fmaf(sf, cs, si * gt2);
    float Ec = ex2(cs);
    float tc = __builtin_fmaf(-2.0f, rcpf(1.0f + Ec), 1.0f);
    return so * tc;
}

__global__ __launch_bounds__(512, 2)
void lstm_ar_kernel(const float* __restrict__ x_in,
                    const float* __restrict__ dly_in,
                    const float* __restrict__ W_ih1, const float* __restrict__ W_hh1,
                    const float* __restrict__ b_ih1, const float* __restrict__ b_hh1,
                    const float* __restrict__ W_ih2, const float* __restrict__ W_hh2,
                    const float* __restrict__ b_ih2, const float* __restrict__ b_hh2,
                    const float* __restrict__ W_out, const float* __restrict__ b_out,
                    float* __restrict__ out)
{
    // h1 rows: upos1 order [hi 0..63 | lo 64..127], stride 136 us (272B).
    // h2 rows: upos2 order [hi 0..31 | lo 32..63],  stride 72 us (144B).
    __shared__ __align__(16) us H1[2][16][136];
    __shared__ __align__(16) us H2[2][16][72];

    const f32x4 ZERO4 = {0.f, 0.f, 0.f, 0.f};

    const int tid = threadIdx.x, w = tid >> 6, l = tid & 63;
    const int lb = l & 15, lq = l >> 4;
    const int bglob = blockIdx.x * 16 + lb;

    for (int i = tid; i < 2*16*136; i += 512) ((us*)H1)[i] = 0;
    for (int i = tid; i < 2*16*72;  i += 512) ((us*)H2)[i] = 0;

    const int ty = lb & 3, du = lb >> 2;
    const float srow = (ty == 2) ? 2.0f * LOG2E : -LOG2E;
    const bool isA = (w < 4);
    const int  w2  = w & 3;

    short8 w1h[4][2], w1l[4][2], wxd[4];                     // A role
    short8 w2h[2][2], w2l[2][2], whh[2], whl[2], wbb[2];     // B role
    short8 wyh = {}, wyl = {};

    if (isA) {
        #pragma unroll
        for (int m = 0; m < 4; ++m) {
            const int G = ty * 64 + 16 * w + 4 * m + du;
            #pragma unroll
            for (int s = 0; s < 2; ++s)
                #pragma unroll
                for (int i = 0; i < 8; ++i) {
                    int p = 32*s + 8*lq + i;
                    float v = srow * W_hh1[G * 64 + upos1(p)];
                    float vh = hmask(v);
                    w1h[m][s][i] = (short)bhi(v);
                    w1l[m][s][i] = (short)bhi(v - vh);
                }
            float q4 = 0.25f * srow;
            float wx = q4 * W_ih1[G*2+0], wd = q4 * W_ih1[G*2+1];
            float bb = q4 * (b_ih1[G] + b_hh1[G]);
            float wxh = hmask(wx), wdh = hmask(wd), bbh = hmask(bb);
            wxd[m] = (short8){ (short)bhi(wx), (short)bhi(wx), (short)bhi(wd),
                               (short)bhi(wd), (short)bhi(bb), (short)bhi(wx - wxh),
                               (short)bhi(wd - wdh), (short)bhi(bb - bbh) };
        }
    } else {
        #pragma unroll
        for (int j = 0; j < 2; ++j) {
            const int G2 = ty * 32 + 8 * w2 + 4 * j + du;
            #pragma unroll
            for (int s = 0; s < 2; ++s)
                #pragma unroll
                for (int i = 0; i < 8; ++i) {
                    int p = 32*s + 8*lq + i;
                    float v = srow * W_ih2[G2 * 64 + upos1(p)];   // h1 pos-order
                    float vh = hmask(v);
                    w2h[j][s][i] = (short)bhi(v);
                    w2l[j][s][i] = (short)bhi(v - vh);
                }
            #pragma unroll
            for (int i = 0; i < 8; ++i) {
                float v = srow * W_hh2[G2 * 32 + upos2(8*lq + i)]; // h2 pos-order
                float vh = hmask(v);
                whh[j][i] = (short)bhi(v);
                whl[j][i] = (short)bhi(v - vh);
            }
            float bb = 0.25f * srow * (b_ih2[G2] + b_hh2[G2]);
            float bbh = hmask(bb);
            wbb[j] = (short8){ (short)bhi(bb), (short)bhi(bb - bbh), 0,0,0,0,0,0 };
        }
        if (w == 4) {
            #pragma unroll
            for (int i = 0; i < 8; ++i) {
                float v = (lb == 0) ? W_out[upos2(8*lq + i)] : 0.0f;
                float vh = hmask(v);
                wyh[i] = (short)bhi(v);
                wyl[i] = (short)bhi(v - vh);
            }
        }
    }
    const float bout = b_out[0];
    const short8 bB = (short8){(short)0x3F80,(short)0x3F80,0,0,0,0,0,0};

    const float* xp = x_in   + bglob * T;
    const float* dp = dly_in + bglob * T;
    float*       op = out    + bglob * T;

    float c1[4] = {0.f,0.f,0.f,0.f};
    float c2[2] = {0.f,0.f};
    f32x4 qA[2] = {ZERO4, ZERO4};
    f32x4 qB[2] = {ZERO4, ZERO4};
    f32x4 qC[2] = {ZERO4, ZERO4};
    float2 xc = {0,0}, dc = {0,0};
    if (isA) { xc = *(const float2*)xp; dc = *(const float2*)dp; }

    __syncthreads();

    auto STEP = [&](const int t, const int pw, const int pr,
                    const float xv, const float dv) {
        if (isA) {
            // ===== HALF 1: MFMA_L1(t), reading h1(t-1) [slot pr] =====
            f32x4 a0[4], a1[4];
            if (t < T) {
                const us* r1 = &H1[pr][lb][0];
                short8 hh0 = *(const short8*)(r1 + 8*lq);
                short8 hh1 = *(const short8*)(r1 + 32 + 8*lq);
                short8 hl0 = *(const short8*)(r1 + 64 + 8*lq);
                short8 hl1 = *(const short8*)(r1 + 96 + 8*lq);
                uu xu = __float_as_uint(xv), duu = __float_as_uint(dv);
                float xlo = xv - __uint_as_float(xu & 0xFFFF0000u);
                float dlo = dv - __uint_as_float(duu & 0xFFFF0000u);
                short8 bx;
                ((uu*)&bx)[0] = (xu >> 16)  | (__float_as_uint(xlo) & 0xFFFF0000u);
                ((uu*)&bx)[1] = (duu >> 16) | (__float_as_uint(dlo) & 0xFFFF0000u);
                ((uu*)&bx)[2] = 0x00003F80u | (xu & 0xFFFF0000u);
                ((uu*)&bx)[3] = (duu >> 16) | 0x3F800000u;
                #pragma unroll
                for (int m = 0; m < 4; ++m) a0[m] = MFMA16(w1h[m][0], hh0, ZERO4);
                #pragma unroll
                for (int m = 0; m < 4; ++m) a1[m] = MFMA16(w1h[m][1], hh1, ZERO4);
                #pragma unroll
                for (int m = 0; m < 4; ++m) a0[m] = MFMA16(w1h[m][0], hl0, a0[m]);
                #pragma unroll
                for (int m = 0; m < 4; ++m) a1[m] = MFMA16(w1h[m][1], hl1, a1[m]);
                #pragma unroll
                for (int m = 0; m < 4; ++m) a0[m] = MFMA16(w1l[m][0], hh0, a0[m]);
                #pragma unroll
                for (int m = 0; m < 4; ++m) a1[m] = MFMA16(w1l[m][1], hh1, a1[m]);
                #pragma unroll
                for (int m = 0; m < 4; ++m) a0[m] = MFMA16(wxd[m], bx, a0[m]);
            }
            SCHEDB(); BARRIER(); SCHEDB();            // BAR1
            // ===== HALF 2: ACT_L1 -> h1(t) [slot pw] =====
            if (t < T) {
                float hv[4];
                #pragma unroll
                for (int m = 0; m < 4; ++m) {
                    f32x4 g = { a0[m][0]+a1[m][0], a0[m][1]+a1[m][1],
                                a0[m][2]+a1[m][2], a0[m][3]+a1[m][3] };
                    hv[m] = actf(g, c1[m]);
                }
                uu P0 = (__float_as_uint(hv[0]) >> 16) | (__float_as_uint(hv[1]) & 0xFFFF0000u);
                uu P1 = (__float_as_uint(hv[2]) >> 16) | (__float_as_uint(hv[3]) & 0xFFFF0000u);
                float e0 = hv[0]-hmask(hv[0]), e1 = hv[1]-hmask(hv[1]);
                float e2 = hv[2]-hmask(hv[2]), e3 = hv[3]-hmask(hv[3]);
                uu Q0 = (__float_as_uint(e0) >> 16) | (__float_as_uint(e1) & 0xFFFF0000u);
                uu Q1 = (__float_as_uint(e2) >> 16) | (__float_as_uint(e3) & 0xFFFF0000u);
                *(uint2*)&H1[pw][lb][16*w + 4*lq]      = (uint2){P0, P1};
                *(uint2*)&H1[pw][lb][64 + 16*w + 4*lq] = (uint2){Q0, Q1};
            }
            SCHEDB(); BARRIER(); SCHEDB();            // BAR2
        } else {
            // ===== HALF 1: ACT_L2 on carried accs -> h2(t-2) [slot pw] =====
            if (t >= 2 && t <= T + 1) {
                float h2v[2];
                #pragma unroll
                for (int j = 0; j < 2; ++j) {
                    f32x4 g = { qA[j][0]+qB[j][0]+qC[j][0], qA[j][1]+qB[j][1]+qC[j][1],
                                qA[j][2]+qB[j][2]+qC[j][2], qA[j][3]+qB[j][3]+qC[j][3] };
                    h2v[j] = actf(g, c2[j]);
                }
                uu ph = (__float_as_uint(h2v[0]) >> 16) | (__float_as_uint(h2v[1]) & 0xFFFF0000u);
                float e0 = h2v[0]-hmask(h2v[0]), e1 = h2v[1]-hmask(h2v[1]);
                uu pl = (__float_as_uint(e0) >> 16) | (__float_as_uint(e1) & 0xFFFF0000u);
                *(uu*)&H2[pw][lb][8*w2 + 2*lq]      = ph;
                *(uu*)&H2[pw][lb][32 + 8*w2 + 2*lq] = pl;
            }
            SCHEDB(); BARRIER(); SCHEDB();            // BAR1 (publishes h2(t-2))
            // ===== HALF 2: MFMA_L2 gates(t-1) + y(t-2) =====
            const bool mm = (t >= 1 && t <= T);
            const bool yy = (w == 4) && (t >= 2) && (t <= T + 1);
            if (mm || yy) {
                const us* r2 = &H2[pw][lb][0];          // h2(t-2)
                short8 ghi = *(const short8*)(r2 + 8*lq);
                short8 glo = *(const short8*)(r2 + 32 + 8*lq);
                if (yy) {
                    f32x4 yA = MFMA16(wyh, ghi, ZERO4);
                    f32x4 yB = MFMA16(wyh, glo, ZERO4);
                    yA = MFMA16(wyl, ghi, yA);
                    if (lq == 0) op[t - 2] = yA[0] + yB[0] + bout;
                }
                if (mm) {
                    const us* r1 = &H1[pr][lb][0];      // h1(t-1)
                    short8 hh0 = *(const short8*)(r1 + 8*lq);
                    short8 hh1 = *(const short8*)(r1 + 32 + 8*lq);
                    short8 hl0 = *(const short8*)(r1 + 64 + 8*lq);
                    short8 hl1 = *(const short8*)(r1 + 96 + 8*lq);
                    #pragma unroll
                    for (int j = 0; j < 2; ++j) {
                        qA[j] = MFMA16(w2h[j][0], hh0, ZERO4);
                        qB[j] = MFMA16(w2h[j][1], hh1, ZERO4);
                        qC[j] = MFMA16(whh[j],    ghi, ZERO4);
                    }
                    #pragma unroll
                    for (int j = 0; j < 2; ++j) {
                        qA[j] = MFMA16(w2h[j][0], hl0, qA[j]);
                        qB[j] = MFMA16(w2h[j][1], hl1, qB[j]);
                        qC[j] = MFMA16(whh[j],    glo, qC[j]);
                    }
                    #pragma unroll
                    for (int j = 0; j < 2; ++j) {
                        qA[j] = MFMA16(w2l[j][0], hh0, qA[j]);
                        qB[j] = MFMA16(w2l[j][1], hh1, qB[j]);
                        qC[j] = MFMA16(whl[j],    ghi, qC[j]);
                    }
                    #pragma unroll
                    for (int j = 0; j < 2; ++j)
                        qC[j] = MFMA16(wbb[j], bB, qC[j]);
                }
            }
            SCHEDB(); BARRIER(); SCHEDB();            // BAR2
        }
    };

    #pragma unroll 1
    for (int tt = 0; tt <= 512; ++tt) {
        float2 xn = xc, dn = dc;
        if (isA) {
            const int wn = (tt < 511) ? tt + 1 : 511;
            xn = *(const float2*)(xp + 2*wn);
            dn = *(const float2*)(dp + 2*wn);
        }
        STEP(2*tt,     0, 1, xc.x, dc.x);
        STEP(2*tt + 1, 1, 0, xc.y, dc.y);
        xc = xn; dc = dn;
    }
}

extern "C" void kernel_launch(void* const* d_in, const int* in_sizes, int n_in,
                              void* d_out, int out_size, void* d_ws, size_t ws_size,
                              hipStream_t stream) {
    lstm_ar_kernel<<<dim3(64), dim3(512), 0, stream>>>(
        (const float*)d_in[0],  (const float*)d_in[1],
        (const float*)d_in[2],  (const float*)d_in[3],
        (const float*)d_in[4],  (const float*)d_in[5],
        (const float*)d_in[6],  (const float*)d_in[7],
        (const float*)d_in[8],  (const float*)d_in[9],
        (const float*)d_in[10], (const float*)d_in[11],
        (float*)d_out);
}

// Round 9
// 831.685 us; speedup vs baseline: 1.2452x; 1.1507x over previous
//
#include <hip/hip_runtime.h>

// LSTMAutoRegressive: B=1024, T=1024, H1=64, H2=32, n_in=n_out=1.
// v8 = v5 base (best: 791us) + joint-rcp actf (7 trans/unit, v6-proven) +
// float4 x/d prefetch. Model: MFMA blocks its SIMD's issue port for its pipe
// duration -> MFMA+VALU issue cycles ADD per SIMD; minimize total issue work.
// 64 wgs x 512 threads. Role-split: w0-3 L1 (4 tiles), w4-7 L2 (2 tiles)+y.
// MFMA 16x16x32 bf16 swapped operands, gate-permuted A-rows, bf16 hi/lo,
// exp2-folded weights, xd folded as 7th MFMA k-step, 1 lgkm-barrier/step.

using short8 = __attribute__((ext_vector_type(8))) short;
using f32x4  = __attribute__((ext_vector_type(4))) float;
typedef unsigned short us;
typedef unsigned int   uu;

#define MFMA16(A,B,C) __builtin_amdgcn_mfma_f32_16x16x32_bf16((A),(B),(C),0,0,0)
#define BARRIER() asm volatile("s_waitcnt lgkmcnt(0)\n\ts_barrier" ::: "memory")

constexpr int   T     = 1024;
constexpr float LOG2E = 1.44269504088896f;

__device__ __forceinline__ us    bhi(float f){ return (us)(__float_as_uint(f) >> 16); }
__device__ __forceinline__ float hmask(float f){ return __uint_as_float(__float_as_uint(f) & 0xFFFF0000u); }
// k-pos -> unit permutations (match packed h write layouts)
__device__ __forceinline__ int upos1(int p){ return 16*(p>>4) + 4*(p&3) + ((p>>2)&3); }
__device__ __forceinline__ int upos2(int p){ return 8*(p>>3) + 4*(p&1) + ((p&7)>>1); }

__device__ __forceinline__ float rcpf(float x){ return __builtin_amdgcn_rcpf(x); }
#if __has_builtin(__builtin_amdgcn_exp2f)
__device__ __forceinline__ float ex2(float x){ return __builtin_amdgcn_exp2f(x); }
#else
__device__ __forceinline__ float ex2(float x){
    float r; asm("v_exp_f32 %0, %1\n\ts_nop 0" : "=v"(r) : "v"(x)); return r;
}
#endif

// gates pre-scaled: i,f,o by -log2e ; g by +2log2e. cs = 2log2e*c carried.
// Joint reciprocal: 1 rcp for 4 gates + 1 for tanh(c): 5 exp + 2 rcp.
__device__ __forceinline__ float actf(const f32x4 a, float& cs){
    float Ei = ex2(a[0]), Ef = ex2(a[1]), Eg = ex2(a[2]), Eo = ex2(a[3]);
    float pi = 1.0f + Ei, pf = 1.0f + Ef, pg = 1.0f + Eg, po = 1.0f + Eo;
    float pif = pi * pf, pgo = pg * po;
    float r   = rcpf(pif * pgo);
    float rif = r * pgo, rgo = r * pif;
    float si = rif * pf, sf = rif * pi;
    float rg = rgo * po, so = rgo * pg;
    float gt2 = __builtin_fmaf(-4.0f * LOG2E, rg, 2.0f * LOG2E);   // 2log2e*tanh(g)
    cs = __builtin_fmaf(sf, cs, si * gt2);
    float Ec = ex2(cs);
    float tc = __builtin_fmaf(-2.0f, rcpf(1.0f + Ec), 1.0f);       // tanh(c)
    return so * tc;
}

__global__ __launch_bounds__(512, 2)
void lstm_ar_kernel(const float* __restrict__ x_in,
                    const float* __restrict__ dly_in,
                    const float* __restrict__ W_ih1, const float* __restrict__ W_hh1,
                    const float* __restrict__ b_ih1, const float* __restrict__ b_hh1,
                    const float* __restrict__ W_ih2, const float* __restrict__ W_hh2,
                    const float* __restrict__ b_ih2, const float* __restrict__ b_hh2,
                    const float* __restrict__ W_out, const float* __restrict__ b_out,
                    float* __restrict__ out)
{
    // h1 rows: upos1 order [hi 0..63 | lo 64..127], stride 136 us (272B).
    // h2 rows: upos2 order [hi 0..31 | lo 32..63],  stride 72 us (144B).
    __shared__ __align__(16) us H1[2][16][136];
    __shared__ __align__(16) us H2[2][16][72];

    const int tid = threadIdx.x, w = tid >> 6, l = tid & 63;
    const int lb = l & 15, lq = l >> 4;
    const int bglob = blockIdx.x * 16 + lb;

    for (int i = tid; i < 2*16*136; i += 512) ((us*)H1)[i] = 0;
    for (int i = tid; i < 2*16*72;  i += 512) ((us*)H2)[i] = 0;

    const int ty = lb & 3, du = lb >> 2;
    const float srow = (ty == 2) ? 2.0f * LOG2E : -LOG2E;
    const bool isA = (w < 4);
    const int  w2  = w & 3;

    // A role: 4 L1 tiles. B role: 2 L2 tiles (+ y on w4).
    short8 w1h[4][2], w1l[4][2], wxd[4];
    short8 w2h[2][2], w2l[2][2], whh[2], whl[2], wbb[2];
    short8 wyh = {}, wyl = {};

    if (isA) {
        #pragma unroll
        for (int m = 0; m < 4; ++m) {
            const int G = ty * 64 + 16 * w + 4 * m + du;
            #pragma unroll
            for (int s = 0; s < 2; ++s)
                #pragma unroll
                for (int i = 0; i < 8; ++i) {
                    int p = 32*s + 8*lq + i;
                    float v = srow * W_hh1[G * 64 + upos1(p)];
                    float vh = hmask(v);
                    w1h[m][s][i] = (short)bhi(v);
                    w1l[m][s][i] = (short)bhi(v - vh);
                }
            float q4 = 0.25f * srow;
            float wx = q4 * W_ih1[G*2+0], wd = q4 * W_ih1[G*2+1];
            float bb = q4 * (b_ih1[G] + b_hh1[G]);
            float wxh = hmask(wx), wdh = hmask(wd), bbh = hmask(bb);
            wxd[m] = (short8){ (short)bhi(wx), (short)bhi(wx), (short)bhi(wd),
                               (short)bhi(wd), (short)bhi(bb), (short)bhi(wx - wxh),
                               (short)bhi(wd - wdh), (short)bhi(bb - bbh) };
        }
    } else {
        #pragma unroll
        for (int j = 0; j < 2; ++j) {
            const int G2 = ty * 32 + 8 * w2 + 4 * j + du;
            #pragma unroll
            for (int s = 0; s < 2; ++s)
                #pragma unroll
                for (int i = 0; i < 8; ++i) {
                    int p = 32*s + 8*lq + i;
                    float v = srow * W_ih2[G2 * 64 + upos1(p)];   // h1 pos-order
                    float vh = hmask(v);
                    w2h[j][s][i] = (short)bhi(v);
                    w2l[j][s][i] = (short)bhi(v - vh);
                }
            #pragma unroll
            for (int i = 0; i < 8; ++i) {
                float v = srow * W_hh2[G2 * 32 + upos2(8*lq + i)]; // h2 pos-order
                float vh = hmask(v);
                whh[j][i] = (short)bhi(v);
                whl[j][i] = (short)bhi(v - vh);
            }
            float bb = 0.25f * srow * (b_ih2[G2] + b_hh2[G2]);
            float bbh = hmask(bb);
            wbb[j] = (short8){ (short)bhi(bb), (short)bhi(bb - bbh), 0,0,0,0,0,0 };
        }
        if (w == 4) {
            #pragma unroll
            for (int i = 0; i < 8; ++i) {
                float v = (lb == 0) ? W_out[upos2(8*lq + i)] : 0.0f;
                float vh = hmask(v);
                wyh[i] = (short)bhi(v);
                wyl[i] = (short)bhi(v - vh);
            }
        }
    }
    const float bout = b_out[0];
    const short8 bB = (short8){(short)0x3F80,(short)0x3F80,0,0,0,0,0,0};
    const f32x4  Z4 = {0.f,0.f,0.f,0.f};

    const float* xp = x_in   + bglob * T;
    const float* dp = dly_in + bglob * T;
    float*       op = out    + bglob * T;

    float c1[4] = {0.f,0.f,0.f,0.f};   // A: 4 units; B: c1[0..1] used for c2
    float4 xc = {0,0,0,0}, dc = {0,0,0,0};
    if (isA) { xc = *(const float4*)xp; dc = *(const float4*)dp; }

    __syncthreads();

    auto STEP = [&](const int t, const int pw, const int pr,
                    const float xv, const float dv) {
        if (isA) {
            if (t < T) {
                const us* r1 = &H1[pr][lb][0];
                short8 hh0 = *(const short8*)(r1 + 8*lq);
                short8 hh1 = *(const short8*)(r1 + 32 + 8*lq);
                short8 hl0 = *(const short8*)(r1 + 64 + 8*lq);
                short8 hl1 = *(const short8*)(r1 + 96 + 8*lq);
                uu xu = __float_as_uint(xv), duu = __float_as_uint(dv);
                float xlo = xv - __uint_as_float(xu & 0xFFFF0000u);
                float dlo = dv - __uint_as_float(duu & 0xFFFF0000u);
                short8 bx;
                ((uu*)&bx)[0] = (xu >> 16)  | (__float_as_uint(xlo) & 0xFFFF0000u);
                ((uu*)&bx)[1] = (duu >> 16) | (__float_as_uint(dlo) & 0xFFFF0000u);
                ((uu*)&bx)[2] = 0x00003F80u | (xu & 0xFFFF0000u);
                ((uu*)&bx)[3] = (duu >> 16) | 0x3F800000u;

                f32x4 a0[4], a1[4];
                #pragma unroll
                for (int m = 0; m < 4; ++m) a0[m] = MFMA16(w1h[m][0], hh0, Z4);
                #pragma unroll
                for (int m = 0; m < 4; ++m) a1[m] = MFMA16(w1h[m][1], hh1, Z4);
                #pragma unroll
                for (int m = 0; m < 4; ++m) a0[m] = MFMA16(w1h[m][0], hl0, a0[m]);
                #pragma unroll
                for (int m = 0; m < 4; ++m) a1[m] = MFMA16(w1h[m][1], hl1, a1[m]);
                #pragma unroll
                for (int m = 0; m < 4; ++m) a0[m] = MFMA16(w1l[m][0], hh0, a0[m]);
                #pragma unroll
                for (int m = 0; m < 4; ++m) a1[m] = MFMA16(w1l[m][1], hh1, a1[m]);
                #pragma unroll
                for (int m = 0; m < 4; ++m) a0[m] = MFMA16(wxd[m], bx, a0[m]);

                float hv[4];
                #pragma unroll
                for (int m = 0; m < 4; ++m) {
                    f32x4 g = { a0[m][0]+a1[m][0], a0[m][1]+a1[m][1],
                                a0[m][2]+a1[m][2], a0[m][3]+a1[m][3] };
                    hv[m] = actf(g, c1[m]);
                }
                uu P0 = (__float_as_uint(hv[0]) >> 16) | (__float_as_uint(hv[1]) & 0xFFFF0000u);
                uu P1 = (__float_as_uint(hv[2]) >> 16) | (__float_as_uint(hv[3]) & 0xFFFF0000u);
                float e0 = hv[0]-hmask(hv[0]), e1 = hv[1]-hmask(hv[1]);
                float e2 = hv[2]-hmask(hv[2]), e3 = hv[3]-hmask(hv[3]);
                uu Q0 = (__float_as_uint(e0) >> 16) | (__float_as_uint(e1) & 0xFFFF0000u);
                uu Q1 = (__float_as_uint(e2) >> 16) | (__float_as_uint(e3) & 0xFFFF0000u);
                *(uint2*)&H1[pw][lb][16*w + 4*lq]      = (uint2){P0, P1};
                *(uint2*)&H1[pw][lb][64 + 16*w + 4*lq] = (uint2){Q0, Q1};
            }
        } else {
            // y(t-2) on wave 4 (independent of this step's chains)
            if (w == 4 && t >= 2) {
                const us* r2p = &H2[pw][lb][0];     // h2(t-2)
                short8 g0 = *(const short8*)(r2p + 8*lq);
                short8 g1 = *(const short8*)(r2p + 32 + 8*lq);
                f32x4 yA = MFMA16(wyh, g0, Z4);
                f32x4 yB = MFMA16(wyh, g1, Z4);
                yA = MFMA16(wyl, g0, yA);
                if (lq == 0) op[t-2] = yA[0] + yB[0] + bout;
            }
            // L2: h2(t-1) from h1(t-1) [slot pr] and h2(t-2) [slot pw]
            if (t >= 1 && t <= T) {
                const us* r1 = &H1[pr][lb][0];
                const us* r2 = &H2[pw][lb][0];
                short8 hh0 = *(const short8*)(r1 + 8*lq);
                short8 hh1 = *(const short8*)(r1 + 32 + 8*lq);
                short8 hl0 = *(const short8*)(r1 + 64 + 8*lq);
                short8 hl1 = *(const short8*)(r1 + 96 + 8*lq);
                short8 g0  = *(const short8*)(r2 + 8*lq);
                short8 g1  = *(const short8*)(r2 + 32 + 8*lq);

                f32x4 qA[2], qB[2], qC[2];
                #pragma unroll
                for (int j = 0; j < 2; ++j) {
                    qA[j] = MFMA16(w2h[j][0], hh0, Z4);
                    qB[j] = MFMA16(w2h[j][1], hh1, Z4);
                    qC[j] = MFMA16(whh[j],    g0,  Z4);
                }
                #pragma unroll
                for (int j = 0; j < 2; ++j) {
                    qA[j] = MFMA16(w2h[j][0], hl0, qA[j]);
                    qB[j] = MFMA16(w2h[j][1], hl1, qB[j]);
                    qC[j] = MFMA16(whh[j],    g1,  qC[j]);
                }
                #pragma unroll
                for (int j = 0; j < 2; ++j) {
                    qA[j] = MFMA16(w2l[j][0], hh0, qA[j]);
                    qB[j] = MFMA16(w2l[j][1], hh1, qB[j]);
                    qC[j] = MFMA16(whl[j],    g0,  qC[j]);
                }
                #pragma unroll
                for (int j = 0; j < 2; ++j)
                    qC[j] = MFMA16(wbb[j], bB, qC[j]);

                float h2v[2];
                #pragma unroll
                for (int j = 0; j < 2; ++j) {
                    f32x4 g = { qA[j][0]+qB[j][0]+qC[j][0], qA[j][1]+qB[j][1]+qC[j][1],
                                qA[j][2]+qB[j][2]+qC[j][2], qA[j][3]+qB[j][3]+qC[j][3] };
                    h2v[j] = actf(g, c1[j]);
                }
                uu ph = (__float_as_uint(h2v[0]) >> 16) | (__float_as_uint(h2v[1]) & 0xFFFF0000u);
                float e0 = h2v[0]-hmask(h2v[0]), e1 = h2v[1]-hmask(h2v[1]);
                uu pl = (__float_as_uint(e0) >> 16) | (__float_as_uint(e1) & 0xFFFF0000u);
                *(uu*)&H2[pr][lb][8*w2 + 2*lq]      = ph;
                *(uu*)&H2[pr][lb][32 + 8*w2 + 2*lq] = pl;
            }
        }
        BARRIER();
    };

    #pragma unroll 1
    for (int W = 0; W <= 256; ++W) {
        float4 xn = xc, dn = dc;
        if (isA) {
            const int Wn = (W < 255) ? W + 1 : 255;
            xn = *(const float4*)(xp + 4*Wn);
            dn = *(const float4*)(dp + 4*Wn);
        }
        STEP(4*W,     0, 1, xc.x, dc.x);
        STEP(4*W + 1, 1, 0, xc.y, dc.y);
        if (W < 256) {
            STEP(4*W + 2, 0, 1, xc.z, dc.z);
            STEP(4*W + 3, 1, 0, xc.w, dc.w);
        }
        xc = xn; dc = dn;
    }
}

extern "C" void kernel_launch(void* const* d_in, const int* in_sizes, int n_in,
                              void* d_out, int out_size, void* d_ws, size_t ws_size,
                              hipStream_t stream) {
    lstm_ar_kernel<<<dim3(64), dim3(512), 0, stream>>>(
        (const float*)d_in[0],  (const float*)d_in[1],
        (const float*)d_in[2],  (const float*)d_in[3],
        (const float*)d_in[4],  (const float*)d_in[5],
        (const float*)d_in[6],  (const float*)d_in[7],
        (const float*)d_in[8],  (const float*)d_in[9],
        (const float*)d_in[10], (const float*)d_in[11],
        (float*)d_out);
}